// Round 9
// baseline (109.905 us; speedup 1.0000x reference)
//
#include <hip/hip_runtime.h>
#include <stdint.h>

// ---------------- problem constants ----------------
#define B_SZ 8192
#define LOG8 2.0794415416798357f   // -log(1/8)
#define NTILE 4160                 // 128x64 tiles, bj >= 2*bi

typedef __attribute__((ext_vector_type(8))) short short8;
typedef __attribute__((ext_vector_type(4))) float floatx4;

typedef __attribute__((address_space(1))) const uint4 guint4;
typedef __attribute__((address_space(3))) uint4 luint4;

// async global->LDS 16B copy: per-lane global addr, wave-uniform LDS base,
// HW scatters lane l to base + l*16.
__device__ inline void async_cp16(const uint4* g, uint4* l) {
    __builtin_amdgcn_global_load_lds((guint4*)g, (luint4*)l, 16, 0, 0);
}

__device__ inline unsigned short f2bf(float f) {
    unsigned int u = __float_as_uint(f);
    u = (u + 0x7FFFu + ((u >> 16) & 1u)) >> 16;   // RNE
    return (unsigned short)u;
}
__device__ inline float bf2f(unsigned short s) {
    return __uint_as_float(((unsigned int)s) << 16);
}
__device__ inline float wredf(float x) {
#pragma unroll
    for (int o = 32; o; o >>= 1) x += __shfl_down(x, o);
    return x;
}
__device__ inline int wredi(int x) {
#pragma unroll
    for (int o = 32; o; o >>= 1) x += __shfl_down(x, o);
    return x;
}

// ws layout:
//  nrm      bf16[8192*128]   @ 0        (2097152 B)
//  nlq      bf16[8192*8]     @ 2097152  (-(logp+log8), sign-flipped bf16)
//  pb       bf16[8192*8]     @ 2228224
//  aprime   f32[8192]        @ 2359296
//  klslot   f32[4160]        @ 2392064  (per-block, non-atomic)
//  cntslot  u32[4160]        @ 2408704
//  prepslot f32[16*11]       @ 2425344

// ---------------- fused prep (272 blocks x 512) ----------------
__global__ __launch_bounds__(512) void prep_all(
    const float* __restrict__ logits,
    const int* __restrict__ targets,
    const float* __restrict__ routing,
    const float* __restrict__ emb,
    unsigned short* __restrict__ nrm,
    unsigned short* __restrict__ nlq,
    unsigned short* __restrict__ pb,
    float* __restrict__ aprime,
    float* __restrict__ prepslot) {
    __shared__ float pred[8][11];
    const int bid = blockIdx.x;
    const int lane = threadIdx.x & 63;
    const int wave = threadIdx.x >> 6;

    if (bid < 256) {
#pragma unroll
        for (int iter = 0; iter < 4; ++iter) {
            int row = (((iter << 8) + bid) << 3) + wave;
            const float2* e2 = (const float2*)(emb + (size_t)row * 128);
            float2 v = e2[lane];
            float ss = v.x * v.x + v.y * v.y;
            ss = wredf(ss);
            ss = __shfl(ss, 0);
            float inv = rsqrtf(ss);
            ushort2 o;
            o.x = f2bf(v.x * inv);
            o.y = f2bf(v.y * inv);
            ((ushort2*)(nrm + (size_t)row * 128))[lane] = o;
        }
        return;
    }

    int row = ((bid - 256) << 9) + threadIdx.x;

    const float4* r4 = (const float4*)(routing + (size_t)row * 8);
    float4 va = r4[0], vb = r4[1];
    float v[8] = {va.x, va.y, va.z, va.w, vb.x, vb.y, vb.z, vb.w};

    float mx = v[0];
#pragma unroll
    for (int e = 1; e < 8; ++e) mx = fmaxf(mx, v[e]);
    float ex[8], s = 0.f;
#pragma unroll
    for (int e = 0; e < 8; ++e) { ex[e] = expf(v[e] - mx); s += ex[e]; }
    float ls = logf(s);
    float inv_s = 1.f / s;

    union { unsigned short u[8]; uint4 q; } lu, pu;
    float ap = 0.f;
#pragma unroll
    for (int e = 0; e < 8; ++e) {
        unsigned short pe = f2bf(ex[e] * inv_s);
        unsigned short le = f2bf(v[e] - mx - ls + LOG8);
        pu.u[e] = pe;
        lu.u[e] = le ^ 0x8000;             // store -lq (exact sign flip)
        ap += bf2f(pe) * bf2f(le);
    }
    ((uint4*)nlq)[row] = lu.q;
    ((uint4*)pb)[row] = pu.q;
    aprime[row] = ap;

    float eff = 0.f, ent = 0.f;
#pragma unroll
    for (int e = 0; e < 8; ++e) {
        if (v[e] < 0.1f) eff += v[e];
        ent += v[e] * logf(v[e] + 1e-8f);
    }

    const float* lg = logits + (size_t)row * 3;
    float a0 = lg[0], a1 = lg[1], a2 = lg[2];
    float mm = fmaxf(a0, fmaxf(a1, a2));
    float lse = mm + logf(expf(a0 - mm) + expf(a1 - mm) + expf(a2 - mm));
    int tg = targets[row];
    float tv = (tg == 0) ? a0 : ((tg == 1) ? a1 : a2);
    float task = lse - tv;

    task = wredf(task);
    eff = wredf(eff);
    ent = wredf(ent);
    float cs[8];
#pragma unroll
    for (int e = 0; e < 8; ++e) cs[e] = wredf(v[e]);

    if (lane == 0) {
        pred[wave][0] = task;
        pred[wave][1] = eff;
        pred[wave][2] = ent;
#pragma unroll
        for (int e = 0; e < 8; ++e) pred[wave][3 + e] = cs[e];
    }
    __syncthreads();
    if (threadIdx.x < 11) {
        float s2 = 0.f;
#pragma unroll
        for (int w = 0; w < 8; ++w) s2 += pred[w][threadIdx.x];
        prepslot[(bid - 256) * 11 + threadIdx.x] = s2;
    }
}

// ---------------- main: symmetric fused sim-mask + KL ----------------
// 128(i) x 64(j) tiles, bj >= 2*bi (4160 tiles). 512 thr, 8 waves in 2x4;
// each wave computes 64 rows x 16 cols (4x1 C-tiles).
// A panel 32 KB + B panel 16 KB = 48 KB LDS -> 3 blocks/CU.
// All staging via global_load_lds (XOR swizzle on global granule), ONE barrier.
// strip tiles (bj>>1 == bi) hold both orientations of within-block pairs:
// count 1, kl(i,j) only, exclude self. Other tiles: count 2, fused
// kl(i,j)+kl(j,i) = ap_i + ap_j - lq_i.p_j - p_i.lq_j in one MFMA.
__global__ __launch_bounds__(512, 4) void tile_sym(
    const unsigned short* __restrict__ nrm,
    const unsigned short* __restrict__ nlq,
    const unsigned short* __restrict__ pb,
    const float* __restrict__ aprime,
    float* __restrict__ klslot,
    unsigned int* __restrict__ cntslot) {
    __shared__ uint4 sh[3072];   // 48 KB: A[0..2047], B[2048..3071]

    const int t = threadIdx.x;
    const int L = blockIdx.x;
    const int wave = t >> 6, lane = t & 63;

    // decode: T(bi) = bi*(129-bi); bi = floor((129 - sqrt(16641-4L))/2)
    int bi = (int)((129.0f - sqrtf((float)(16641 - 4 * L))) * 0.5f);
    int T = bi * (129 - bi);
    while (L < T) { --bi; T = bi * (129 - bi); }
    while (L >= T + (128 - 2 * bi)) { T += 128 - 2 * bi; ++bi; }
    const int bj = 2 * bi + (L - T);
    const bool strip = ((bj >> 1) == bi);
    const int iBase = bi << 7, jBase = bj << 6;

    const uint4* n4 = (const uint4*)nrm;

    // ---- A panel: 4 issues x 512 granules (128 rows x 16) ----
#pragma unroll
    for (int it = 0; it < 4; ++it) {
        int idx = t + (it << 9);
        int row = idx >> 4, s = idx & 15;
        int g = s ^ (row & 15);
        async_cp16(&n4[((size_t)(iBase + row) << 4) + g],
                   sh + (it << 9) + (wave << 6));
    }
    // ---- B panel: 2 issues x 512 granules (64 rows x 16) ----
#pragma unroll
    for (int it = 0; it < 2; ++it) {
        int idx = t + (it << 9);
        int row = idx >> 4, s = idx & 15;
        int g = s ^ (row & 15);
        async_cp16(&n4[((size_t)(jBase + row) << 4) + g],
                   sh + 2048 + (it << 9) + (wave << 6));
    }

    const int wr = wave >> 2, wc = wave & 3;   // 2 x 4 wave grid
    const int m = lane & 15, q = lane >> 4;
    const short8 zero8 = (short8){0, 0, 0, 0, 0, 0, 0, 0};

    // cross fragments (overlap staging flight):
    //  A: q0 = -lq_i, q1 = p_i (0 on strip), q2: k16=bf16(ap_i)(0 on strip), k17=1
    //  B: q0 = p_j,   q1 = -lq_j,            q2: k16=1, k17=bf16(ap_j)
    short8 crA[4], crB;
#pragma unroll
    for (int a = 0; a < 4; ++a) {
        int ri = iBase + (wr << 6) + (a << 4) + m;
        short8 v = zero8;
        if (q == 0) v = *(const short8*)&nlq[(size_t)ri << 3];
        else if (q == 1) { if (!strip) v = *(const short8*)&pb[(size_t)ri << 3]; }
        else if (q == 2) {
            v[1] = (short)0x3F80;
            if (!strip) v[0] = (short)f2bf(aprime[ri]);
        }
        crA[a] = v;
    }
    {
        int cj = jBase + (wc << 4) + m;
        short8 v = zero8;
        if (q == 0) v = *(const short8*)&pb[(size_t)cj << 3];
        else if (q == 1) v = *(const short8*)&nlq[(size_t)cj << 3];
        else if (q == 2) {
            v[0] = (short)0x3F80;
            v[1] = (short)f2bf(aprime[cj]);
        }
        crB = v;
    }

    __syncthreads();                   // drains all async staging

    floatx4 simacc[4];
#pragma unroll
    for (int a = 0; a < 4; ++a) simacc[a] = (floatx4){0.f, 0.f, 0.f, 0.f};

    // ---- sim = A . B^T over K=128 ----
#pragma unroll
    for (int ks = 0; ks < 4; ++ks) {
        const int gk = (ks << 2) + q;
        short8 bfr;
        {
            int rb = (wc << 4) + m;                  // rb & 15 == m
            bfr = *(const short8*)(sh + 2048 + (rb << 4) + (gk ^ m));
        }
        short8 af[4];
#pragma unroll
        for (int a = 0; a < 4; ++a) {
            int row = (wr << 6) + (a << 4) + m;      // row & 15 == m
            af[a] = *(const short8*)(sh + (row << 4) + (gk ^ m));
        }
#pragma unroll
        for (int a = 0; a < 4; ++a)
            simacc[a] = __builtin_amdgcn_mfma_f32_16x16x32_bf16(
                af[a], bfr, simacc[a], 0, 0, 0);
    }

    // ---- epilogue: kl via one MFMA per C-tile, masked accumulate ----
    float klLocal = 0.f;
    int cntLocal = 0;
    const int gCol = jBase + (wc << 4) + m;
#pragma unroll
    for (int a = 0; a < 4; ++a) {
        const int gRow0 = iBase + (wr << 6) + (a << 4) + (q << 2);
        floatx4 cr = __builtin_amdgcn_mfma_f32_16x16x32_bf16(
            crA[a], crB, (floatx4){0.f, 0.f, 0.f, 0.f}, 0, 0, 0);
        if (strip) {
#pragma unroll
            for (int r = 0; r < 4; ++r) {
                if ((simacc[a][r] > 0.8f) && (gRow0 + r != gCol)) {
                    klLocal += cr[r];
                    cntLocal += 1;
                }
            }
        } else {
#pragma unroll
            for (int r = 0; r < 4; ++r) {
                if (simacc[a][r] > 0.8f) {
                    klLocal += cr[r];
                    cntLocal += 2;
                }
            }
        }
    }

    klLocal = wredf(klLocal);
    cntLocal = wredi(cntLocal);

    __syncthreads();                   // all LDS reads complete
    float* redk = (float*)sh;
    int* redc = (int*)(redk + 8);
    if (lane == 0) { redk[wave] = klLocal; redc[wave] = cntLocal; }
    __syncthreads();

    if (t == 0) {
        float k = 0.f;
        int c = 0;
#pragma unroll
        for (int w = 0; w < 8; ++w) { k += redk[w]; c += redc[w]; }
        klslot[L] = k;                     // unique slot: no atomic
        cntslot[L] = (unsigned int)c;
    }
}

// ---------------- finalize (1 block x 256) ----------------
__global__ void finalize_k(const float* __restrict__ klslot,
                           const unsigned int* __restrict__ cntslot,
                           const float* __restrict__ prepslot,
                           const float* __restrict__ temp,
                           float* __restrict__ out) {
    __shared__ float sk[4];
    __shared__ int sc[4];
    __shared__ float sp[11];
    const int t = threadIdx.x, lane = t & 63, wave = t >> 6;

    float k = 0.f;
    int c = 0;
    for (int i = t; i < NTILE; i += 256) { k += klslot[i]; c += (int)cntslot[i]; }
    k = wredf(k);
    c = wredi(c);
    if (lane == 0) { sk[wave] = k; sc[wave] = c; }
    if (t < 11) {
        float s = 0.f;
        for (int r = 0; r < 16; ++r) s += prepslot[r * 11 + t];
        sp[t] = s;
    }
    __syncthreads();
    if (t == 0) {
        float K = sk[0] + sk[1] + sk[2] + sk[3];
        int C = sc[0] + sc[1] + sc[2] + sc[3];
        const float invB = 1.f / (float)B_SZ;
        float task = sp[0] * invB;
        float eff = 0.05f * sp[1] * invB;
        float entl = 0.01f * sp[2] * invB;
        float cons = 0.1f * (C > 0 ? K / (float)C : 0.f);
        float u[8], mean = 0.f;
        for (int e = 0; e < 8; ++e) { u[e] = sp[3 + e] * invB; mean += u[e]; }
        mean *= 0.125f;
        float var = 0.f;
        for (int e = 0; e < 8; ++e) { float d = u[e] - mean; var += d * d; }
        var *= (1.f / 7.f);                // unbiased (ddof=1)
        float lb = 0.1f * var * 64.f;      // * E^2
        float tt = temp[0] - 1.f;
        out[0] = task + lb + eff + cons + entl + 0.01f * tt * tt;
    }
}

// ---------------- launch ----------------
extern "C" void kernel_launch(void* const* d_in, const int* in_sizes, int n_in,
                              void* d_out, int out_size, void* d_ws, size_t ws_size,
                              hipStream_t stream) {
    const float* logits = (const float*)d_in[0];
    const int* targets = (const int*)d_in[1];
    const float* routing = (const float*)d_in[2];
    const float* emb = (const float*)d_in[3];
    const float* temp = (const float*)d_in[4];

    char* ws = (char*)d_ws;
    unsigned short* nrm = (unsigned short*)ws;
    unsigned short* nlq = (unsigned short*)(ws + 2097152);
    unsigned short* pb = (unsigned short*)(ws + 2228224);
    float* aprime = (float*)(ws + 2359296);
    float* klslot = (float*)(ws + 2392064);
    unsigned int* cntslot = (unsigned int*)(ws + 2408704);
    float* prepslot = (float*)(ws + 2425344);

    prep_all<<<272, 512, 0, stream>>>(logits, targets, routing, emb,
                                      nrm, nlq, pb, aprime, prepslot);
    tile_sym<<<NTILE, 512, 0, stream>>>(nrm, nlq, pb, aprime, klslot, cntslot);
    finalize_k<<<1, 256, 0, stream>>>(klslot, cntslot, prepslot, temp,
                                      (float*)d_out);
}

// Round 10
// 105.855 us; speedup vs baseline: 1.0383x; 1.0383x over previous
//
#include <hip/hip_runtime.h>
#include <stdint.h>

// ---------------- problem constants ----------------
#define B_SZ 8192
#define LOG8 2.0794415416798357f   // -log(1/8)
#define NCHUNK 544                 // blocks: sum_bi ceil((128-2bi)/8)

typedef __attribute__((ext_vector_type(8))) short short8;
typedef __attribute__((ext_vector_type(4))) float floatx4;

typedef __attribute__((address_space(1))) const uint4 guint4;
typedef __attribute__((address_space(3))) uint4 luint4;

// async global->LDS 16B copy: per-lane global addr, wave-uniform LDS base,
// HW scatters lane l to base + l*16.
__device__ inline void async_cp16(const uint4* g, uint4* l) {
    __builtin_amdgcn_global_load_lds((guint4*)g, (luint4*)l, 16, 0, 0);
}

__device__ inline unsigned short f2bf(float f) {
    unsigned int u = __float_as_uint(f);
    u = (u + 0x7FFFu + ((u >> 16) & 1u)) >> 16;   // RNE
    return (unsigned short)u;
}
__device__ inline float bf2f(unsigned short s) {
    return __uint_as_float(((unsigned int)s) << 16);
}
__device__ inline float wredf(float x) {
#pragma unroll
    for (int o = 32; o; o >>= 1) x += __shfl_down(x, o);
    return x;
}
__device__ inline int wredi(int x) {
#pragma unroll
    for (int o = 32; o; o >>= 1) x += __shfl_down(x, o);
    return x;
}

// ws layout:
//  nrm      bf16[8192*128]   @ 0        (2097152 B)
//  nlq      bf16[8192*8]     @ 2097152  (-(logp+log8), sign-flipped bf16)
//  pb       bf16[8192*8]     @ 2228224
//  aprime   f32[8192]        @ 2359296
//  klslot   f32[544]         @ 2392064
//  cntslot  u32[544]         @ 2394304
//  prepslot f32[16*11]       @ 2396544

// ---------------- fused prep (272 blocks x 512) ----------------
__global__ __launch_bounds__(512) void prep_all(
    const float* __restrict__ logits,
    const int* __restrict__ targets,
    const float* __restrict__ routing,
    const float* __restrict__ emb,
    unsigned short* __restrict__ nrm,
    unsigned short* __restrict__ nlq,
    unsigned short* __restrict__ pb,
    float* __restrict__ aprime,
    float* __restrict__ prepslot) {
    __shared__ float pred[8][11];
    const int bid = blockIdx.x;
    const int lane = threadIdx.x & 63;
    const int wave = threadIdx.x >> 6;

    if (bid < 256) {
#pragma unroll
        for (int iter = 0; iter < 4; ++iter) {
            int row = (((iter << 8) + bid) << 3) + wave;
            const float2* e2 = (const float2*)(emb + (size_t)row * 128);
            float2 v = e2[lane];
            float ss = v.x * v.x + v.y * v.y;
            ss = wredf(ss);
            ss = __shfl(ss, 0);
            float inv = rsqrtf(ss);
            ushort2 o;
            o.x = f2bf(v.x * inv);
            o.y = f2bf(v.y * inv);
            ((ushort2*)(nrm + (size_t)row * 128))[lane] = o;
        }
        return;
    }

    int row = ((bid - 256) << 9) + threadIdx.x;

    const float4* r4 = (const float4*)(routing + (size_t)row * 8);
    float4 va = r4[0], vb = r4[1];
    float v[8] = {va.x, va.y, va.z, va.w, vb.x, vb.y, vb.z, vb.w};

    float mx = v[0];
#pragma unroll
    for (int e = 1; e < 8; ++e) mx = fmaxf(mx, v[e]);
    float ex[8], s = 0.f;
#pragma unroll
    for (int e = 0; e < 8; ++e) { ex[e] = expf(v[e] - mx); s += ex[e]; }
    float ls = logf(s);
    float inv_s = 1.f / s;

    union { unsigned short u[8]; uint4 q; } lu, pu;
    float ap = 0.f;
#pragma unroll
    for (int e = 0; e < 8; ++e) {
        unsigned short pe = f2bf(ex[e] * inv_s);
        unsigned short le = f2bf(v[e] - mx - ls + LOG8);
        pu.u[e] = pe;
        lu.u[e] = le ^ 0x8000;             // store -lq (exact sign flip)
        ap += bf2f(pe) * bf2f(le);
    }
    ((uint4*)nlq)[row] = lu.q;
    ((uint4*)pb)[row] = pu.q;
    aprime[row] = ap;

    float eff = 0.f, ent = 0.f;
#pragma unroll
    for (int e = 0; e < 8; ++e) {
        if (v[e] < 0.1f) eff += v[e];
        ent += v[e] * logf(v[e] + 1e-8f);
    }

    const float* lg = logits + (size_t)row * 3;
    float a0 = lg[0], a1 = lg[1], a2 = lg[2];
    float mm = fmaxf(a0, fmaxf(a1, a2));
    float lse = mm + logf(expf(a0 - mm) + expf(a1 - mm) + expf(a2 - mm));
    int tg = targets[row];
    float tv = (tg == 0) ? a0 : ((tg == 1) ? a1 : a2);
    float task = lse - tv;

    task = wredf(task);
    eff = wredf(eff);
    ent = wredf(ent);
    float cs[8];
#pragma unroll
    for (int e = 0; e < 8; ++e) cs[e] = wredf(v[e]);

    if (lane == 0) {
        pred[wave][0] = task;
        pred[wave][1] = eff;
        pred[wave][2] = ent;
#pragma unroll
        for (int e = 0; e < 8; ++e) pred[wave][3 + e] = cs[e];
    }
    __syncthreads();
    if (threadIdx.x < 11) {
        float s2 = 0.f;
#pragma unroll
        for (int w = 0; w < 8; ++w) s2 += pred[w][threadIdx.x];
        prepslot[(bid - 256) * 11 + threadIdx.x] = s2;
    }
}

// ---------------- main: chunked symmetric sim-mask + KL ----------------
// 544 blocks; block = (bi, chunk c): A panel = 128 rows at iBase=bi*128,
// tiles t=0..nt-1 over 128x64 B-strips bj = 2bi + 8c + t (bj >= 2bi).
// LDS: A 32 KB + B double-buffer 2x16 KB = 64 KB. All staging via
// global_load_lds (no VGPR prefetch -> no spills). B(t+1) prefetched async
// during tile t's compute; end-of-iter barrier drains it.
// strip tiles (bj>>1==bi): count 1, exclude self; else count 2 with fused
// kl(i,j)+kl(j,i) = ap_i + ap_j - lq_i.p_j - p_i.lq_j in one MFMA.
__global__ __launch_bounds__(512, 4) void tile_sym(
    const unsigned short* __restrict__ nrm,
    const unsigned short* __restrict__ nlq,
    const unsigned short* __restrict__ pb,
    const float* __restrict__ aprime,
    float* __restrict__ klslot,
    unsigned int* __restrict__ cntslot) {
    __shared__ uint4 sh[4096];   // A: [0..2047], B0: [2048..3071], B1: [3072..4095]

    const int t = threadIdx.x;
    const int wave = t >> 6, lane = t & 63;

    // ---- decode block -> (bi, c) ----
    int bi = 0, rem = blockIdx.x;
    for (;;) {
        int nc = (135 - 2 * bi) >> 3;     // ceil((128-2bi)/8)
        if (rem < nc) break;
        rem -= nc;
        ++bi;
    }
    const int c = rem;
    const int bj0 = 2 * bi + (c << 3);
    const int nt = min(8, 128 - bj0);
    const int iBase = bi << 7;

    const uint4* n4 = (const uint4*)nrm;

    // ---- stage A panel (32 KB, 4 issues) ----
#pragma unroll
    for (int it = 0; it < 4; ++it) {
        int idx = t + (it << 9);          // 0..2047
        int row = idx >> 4, s = idx & 15;
        int g = s ^ (row & 15);
        async_cp16(&n4[((size_t)(iBase + row) << 4) + g],
                   sh + (it << 9) + (wave << 6));
    }
    // ---- stage B0 (16 KB, 2 issues) ----
    {
        const int jB = bj0 << 6;
#pragma unroll
        for (int it = 0; it < 2; ++it) {
            int idx = t + (it << 9);      // 0..1023
            int row = idx >> 4, s = idx & 15;
            int g = s ^ (row & 15);
            async_cp16(&n4[((size_t)(jB + row) << 4) + g],
                       sh + 2048 + (it << 9) + (wave << 6));
        }
    }

    const int wr = wave >> 2, wc = wave & 3;   // 2 x 4 wave grid
    const int m = lane & 15, q = lane >> 4;
    const short8 zero8 = (short8){0, 0, 0, 0, 0, 0, 0, 0};

    // ---- hoisted A-side cross fragments (non-strip form) ----
    //  q0 = -lq_i, q1 = p_i, q2: k16=bf16(ap_i), k17=1
    short8 crA[4];
#pragma unroll
    for (int a = 0; a < 4; ++a) {
        int ri = iBase + (wr << 6) + (a << 4) + m;
        short8 v = zero8;
        if (q == 0) v = *(const short8*)&nlq[(size_t)ri << 3];
        else if (q == 1) v = *(const short8*)&pb[(size_t)ri << 3];
        else if (q == 2) {
            v[0] = (short)f2bf(aprime[ri]);
            v[1] = (short)0x3F80;
        }
        crA[a] = v;
    }

    __syncthreads();                   // drains A + B0

    float klLocal = 0.f;
    int cntLocal = 0;

#pragma unroll 1
    for (int tt = 0; tt < nt; ++tt) {
        const int bj = bj0 + tt;
        const int jBase = bj << 6;
        const bool strip = ((bj >> 1) == bi);
        const int cur = 2048 + ((tt & 1) << 10);

        // prefetch next B strip into the other buffer (async, no regs)
        if (tt + 1 < nt) {
            const int jN = (bj + 1) << 6;
            const int nxt = 2048 + (((tt + 1) & 1) << 10);
#pragma unroll
            for (int it = 0; it < 2; ++it) {
                int idx = t + (it << 9);
                int row = idx >> 4, s = idx & 15;
                int g = s ^ (row & 15);
                async_cp16(&n4[((size_t)(jN + row) << 4) + g],
                           sh + nxt + (it << 9) + (wave << 6));
            }
        }

        // B-side cross fragment for this strip
        short8 crB;
        {
            int cj = jBase + (wc << 4) + m;
            short8 v = zero8;
            if (q == 0) v = *(const short8*)&pb[(size_t)cj << 3];
            else if (q == 1) v = *(const short8*)&nlq[(size_t)cj << 3];
            else if (q == 2) {
                v[0] = (short)0x3F80;
                v[1] = (short)f2bf(aprime[cj]);
            }
            crB = v;
        }

        // ---- sim = A . B^T over K=128 ----
        floatx4 simacc[4];
#pragma unroll
        for (int a = 0; a < 4; ++a) simacc[a] = (floatx4){0.f, 0.f, 0.f, 0.f};
#pragma unroll
        for (int ks = 0; ks < 4; ++ks) {
            const int gk = (ks << 2) + q;
            short8 bfr;
            {
                int rb = (wc << 4) + m;              // rb & 15 == m
                bfr = *(const short8*)(sh + cur + (rb << 4) + (gk ^ m));
            }
            short8 af[4];
#pragma unroll
            for (int a = 0; a < 4; ++a) {
                int row = (wr << 6) + (a << 4) + m;  // row & 15 == m
                af[a] = *(const short8*)(sh + (row << 4) + (gk ^ m));
            }
#pragma unroll
            for (int a = 0; a < 4; ++a)
                simacc[a] = __builtin_amdgcn_mfma_f32_16x16x32_bf16(
                    af[a], bfr, simacc[a], 0, 0, 0);
        }

        // ---- epilogue: kl via one MFMA per C-tile ----
        const int gCol = jBase + (wc << 4) + m;
#pragma unroll
        for (int a = 0; a < 4; ++a) {
            short8 ca = crA[a];
            if (strip) {                 // strip: kl(i,j) only
                if (q == 1) ca = zero8;
                else if (q == 2) ca[0] = 0;
            }
            floatx4 cr = __builtin_amdgcn_mfma_f32_16x16x32_bf16(
                ca, crB, (floatx4){0.f, 0.f, 0.f, 0.f}, 0, 0, 0);
            const int gRow0 = iBase + (wr << 6) + (a << 4) + (q << 2);
            if (strip) {
#pragma unroll
                for (int r = 0; r < 4; ++r) {
                    if ((simacc[a][r] > 0.8f) && (gRow0 + r != gCol)) {
                        klLocal += cr[r];
                        cntLocal += 1;
                    }
                }
            } else {
#pragma unroll
                for (int r = 0; r < 4; ++r) {
                    if (simacc[a][r] > 0.8f) {
                        klLocal += cr[r];
                        cntLocal += 2;
                    }
                }
            }
        }

        __syncthreads();               // drains B(t+1); guards buffer reuse
    }

    klLocal = wredf(klLocal);
    cntLocal = wredi(cntLocal);

    float* redk = (float*)sh;
    int* redc = (int*)(redk + 8);
    if (lane == 0) { redk[wave] = klLocal; redc[wave] = cntLocal; }
    __syncthreads();

    if (t == 0) {
        float k = 0.f;
        int cc = 0;
#pragma unroll
        for (int w = 0; w < 8; ++w) { k += redk[w]; cc += redc[w]; }
        klslot[blockIdx.x] = k;            // unique slot: no atomic
        cntslot[blockIdx.x] = (unsigned int)cc;
    }
}

// ---------------- finalize (1 block x 256) ----------------
__global__ void finalize_k(const float* __restrict__ klslot,
                           const unsigned int* __restrict__ cntslot,
                           const float* __restrict__ prepslot,
                           const float* __restrict__ temp,
                           float* __restrict__ out) {
    __shared__ float sk[4];
    __shared__ int sc[4];
    __shared__ float sp[11];
    const int t = threadIdx.x, lane = t & 63, wave = t >> 6;

    float k = 0.f;
    int c = 0;
    for (int i = t; i < NCHUNK; i += 256) { k += klslot[i]; c += (int)cntslot[i]; }
    k = wredf(k);
    c = wredi(c);
    if (lane == 0) { sk[wave] = k; sc[wave] = c; }
    if (t < 11) {
        float s = 0.f;
        for (int r = 0; r < 16; ++r) s += prepslot[r * 11 + t];
        sp[t] = s;
    }
    __syncthreads();
    if (t == 0) {
        float K = sk[0] + sk[1] + sk[2] + sk[3];
        int C = sc[0] + sc[1] + sc[2] + sc[3];
        const float invB = 1.f / (float)B_SZ;
        float task = sp[0] * invB;
        float eff = 0.05f * sp[1] * invB;
        float entl = 0.01f * sp[2] * invB;
        float cons = 0.1f * (C > 0 ? K / (float)C : 0.f);
        float u[8], mean = 0.f;
        for (int e = 0; e < 8; ++e) { u[e] = sp[3 + e] * invB; mean += u[e]; }
        mean *= 0.125f;
        float var = 0.f;
        for (int e = 0; e < 8; ++e) { float d = u[e] - mean; var += d * d; }
        var *= (1.f / 7.f);                // unbiased (ddof=1)
        float lb = 0.1f * var * 64.f;      // * E^2
        float tt = temp[0] - 1.f;
        out[0] = task + lb + eff + cons + entl + 0.01f * tt * tt;
    }
}

// ---------------- launch ----------------
extern "C" void kernel_launch(void* const* d_in, const int* in_sizes, int n_in,
                              void* d_out, int out_size, void* d_ws, size_t ws_size,
                              hipStream_t stream) {
    const float* logits = (const float*)d_in[0];
    const int* targets = (const int*)d_in[1];
    const float* routing = (const float*)d_in[2];
    const float* emb = (const float*)d_in[3];
    const float* temp = (const float*)d_in[4];

    char* ws = (char*)d_ws;
    unsigned short* nrm = (unsigned short*)ws;
    unsigned short* nlq = (unsigned short*)(ws + 2097152);
    unsigned short* pb = (unsigned short*)(ws + 2228224);
    float* aprime = (float*)(ws + 2359296);
    float* klslot = (float*)(ws + 2392064);
    unsigned int* cntslot = (unsigned int*)(ws + 2394304);
    float* prepslot = (float*)(ws + 2396544);

    prep_all<<<272, 512, 0, stream>>>(logits, targets, routing, emb,
                                      nrm, nlq, pb, aprime, prepslot);
    tile_sym<<<NCHUNK, 512, 0, stream>>>(nrm, nlq, pb, aprime, klslot, cntslot);
    finalize_k<<<1, 256, 0, stream>>>(klslot, cntslot, prepslot, temp,
                                      (float*)d_out);
}